// Round 1
// baseline (37381.448 us; speedup 1.0000x reference)
//
#include <hip/hip_runtime.h>

#define SEQ    1024
#define EDIM   1024
#define NHEAD  16
#define DHEAD  64
#define NLAYER 12
#define NTOK   4096   // B*S

typedef float f32x4  __attribute__((ext_vector_type(4)));
typedef short bf16x8 __attribute__((ext_vector_type(8)));

__device__ __forceinline__ unsigned short f32_to_bf16(float f) {
    union { float f; unsigned u; } v; v.f = f;
    return (unsigned short)((v.u + 0x7fffu + ((v.u >> 16) & 1u)) >> 16);
}
__device__ __forceinline__ unsigned pack_bf16x2(float a, float b) {
    return (unsigned)f32_to_bf16(a) | ((unsigned)f32_to_bf16(b) << 16);
}

// ---------------- embedding: h = wte[x] + wpe[s] ----------------
__global__ __launch_bounds__(256) void embed_k(
    const int* __restrict__ x, const float* __restrict__ wte,
    const float* __restrict__ wpe, float* __restrict__ h)
{
    const int bs  = blockIdx.x;            // 0..4095 (b*S + s)
    const int s   = bs & (SEQ - 1);
    const int tok = x[bs];
    const int c   = threadIdx.x * 4;
    float4 a = *reinterpret_cast<const float4*>(&wte[(size_t)tok * EDIM + c]);
    const float4 p = *reinterpret_cast<const float4*>(&wpe[(size_t)s * EDIM + c]);
    a.x += p.x; a.y += p.y; a.z += p.z; a.w += p.w;
    *reinterpret_cast<float4*>(&h[(size_t)bs * EDIM + c]) = a;
}

// ---------------- out = layernorm(x1 (+ x2), g, b) ----------------
__global__ __launch_bounds__(256) void add_ln_k(
    const float* __restrict__ x1, const float* __restrict__ x2,
    const float* __restrict__ g, const float* __restrict__ b,
    float* __restrict__ out)
{
    const int row = blockIdx.x;
    const int t   = threadIdx.x;
    const float* p1 = x1 + (size_t)row * EDIM;
    const float* p2 = x2 ? x2 + (size_t)row * EDIM : nullptr;
    float v[4];
    float s = 0.f, ss = 0.f;
    #pragma unroll
    for (int i = 0; i < 4; ++i) {
        const int c = t + i * 256;
        float a = p1[c];
        if (p2) a += p2[c];
        v[i] = a; s += a; ss += a * a;
    }
    #pragma unroll
    for (int o = 32; o > 0; o >>= 1) {
        s  += __shfl_down(s, o);
        ss += __shfl_down(ss, o);
    }
    __shared__ float rs[4], rss[4];
    const int lane = t & 63, wv = t >> 6;
    if (lane == 0) { rs[wv] = s; rss[wv] = ss; }
    __syncthreads();
    s  = rs[0] + rs[1] + rs[2] + rs[3];
    ss = rss[0] + rss[1] + rss[2] + rss[3];
    const float mean = s * (1.f / EDIM);
    const float var  = ss * (1.f / EDIM) - mean * mean;
    const float inv  = rsqrtf(var + 1e-5f);
    float* po = out + (size_t)row * EDIM;
    #pragma unroll
    for (int i = 0; i < 4; ++i) {
        const int c = t + i * 256;
        po[c] = (v[i] - mean) * inv * g[c] + b[c];
    }
}

// ---------------- GEMM: C = A(MxK,f32) @ B(KxN,f32) + bias, optional exact-gelu ----------------
// bf16 MFMA 16x16x32, fp32 accumulate. Tile 128x128, BK=32, 4 waves (each 64x64 = 4x4 frags).
template<int GELU>
__global__ __launch_bounds__(256) void gemm_bias_k(
    const float* __restrict__ A, const float* __restrict__ B,
    const float* __restrict__ bias, float* __restrict__ C,
    int M, int N, int K)
{
    __shared__ unsigned short As[128][40];   // [m][k], pad 40 -> conflict-free b128 frag reads
    __shared__ unsigned short Bs[32][130];   // [k][n], pad 130 -> conflict-free u16 gathers

    const int t    = threadIdx.x;
    const int lane = t & 63;
    const int wave = t >> 6;
    const int wr   = wave >> 1, wc = wave & 1;   // wave sub-tile (64x64) origin
    const int lrow = lane & 15, lgrp = lane >> 4;
    const int row0 = blockIdx.y * 128, col0 = blockIdx.x * 128;

    f32x4 acc[4][4];
    #pragma unroll
    for (int i = 0; i < 4; ++i)
        #pragma unroll
        for (int j = 0; j < 4; ++j)
            acc[i][j] = (f32x4){0.f, 0.f, 0.f, 0.f};

    for (int k0 = 0; k0 < K; k0 += 32) {
        // stage A tile 128x32 (f32 -> bf16)
        #pragma unroll
        for (int i = 0; i < 4; ++i) {
            const int flat = t + i * 256;           // float4 index, 1024 total
            const int ar = flat >> 3, ac = (flat & 7) * 4;
            const float4 v = *reinterpret_cast<const float4*>(
                &A[(size_t)(row0 + ar) * K + k0 + ac]);
            unsigned* dst = reinterpret_cast<unsigned*>(&As[ar][ac]);
            dst[0] = pack_bf16x2(v.x, v.y);
            dst[1] = pack_bf16x2(v.z, v.w);
        }
        // stage B tile 32x128 (f32 -> bf16)
        #pragma unroll
        for (int i = 0; i < 4; ++i) {
            const int flat = t + i * 256;
            const int br = flat >> 5, bc = (flat & 31) * 4;
            const float4 v = *reinterpret_cast<const float4*>(
                &B[(size_t)(k0 + br) * N + col0 + bc]);
            unsigned* dst = reinterpret_cast<unsigned*>(&Bs[br][bc]);
            dst[0] = pack_bf16x2(v.x, v.y);
            dst[1] = pack_bf16x2(v.z, v.w);
        }
        __syncthreads();

        bf16x8 af[4];
        #pragma unroll
        for (int m = 0; m < 4; ++m)
            af[m] = *reinterpret_cast<const bf16x8*>(
                &As[wr * 64 + m * 16 + lrow][lgrp * 8]);

        #pragma unroll
        for (int n = 0; n < 4; ++n) {
            const int bcol = wc * 64 + n * 16 + lrow;
            bf16x8 bfr;
            #pragma unroll
            for (int j = 0; j < 8; ++j)
                bfr[j] = (short)Bs[lgrp * 8 + j][bcol];
            #pragma unroll
            for (int m = 0; m < 4; ++m)
                acc[m][n] = __builtin_amdgcn_mfma_f32_16x16x32_bf16(
                    af[m], bfr, acc[m][n], 0, 0, 0);
        }
        __syncthreads();
    }

    // epilogue: D layout col = lane&15, row = 4*(lane>>4) + reg  [m89/m91-verified]
    #pragma unroll
    for (int n = 0; n < 4; ++n) {
        const int col = col0 + wc * 64 + n * 16 + lrow;
        const float bv = bias[col];
        #pragma unroll
        for (int m = 0; m < 4; ++m) {
            const int rbase = row0 + wr * 64 + m * 16 + lgrp * 4;
            #pragma unroll
            for (int r = 0; r < 4; ++r) {
                float xv = acc[m][n][r] + bv;
                if (GELU) xv = 0.5f * xv * (1.f + erff(xv * 0.70710678118654752f));
                C[(size_t)(rbase + r) * N + col] = xv;
            }
        }
    }
}

// ---------------- attention: per (b, head, 8 q-rows) block, fp32 ----------------
// scores = q . kv (unscaled), key-padding mask (x==0 -> -1e9), softmax, out = P @ kv
#define QR   8
#define SPAD 1032
__global__ __launch_bounds__(256) void attn_k(
    const float* __restrict__ q, const float* __restrict__ kv,
    const int* __restrict__ x, float* __restrict__ out)
{
    const int qt = blockIdx.x;     // 0..127 (8 rows each)
    const int hh = blockIdx.y;     // head
    const int b  = blockIdx.z;

    __shared__ float qs[QR][DHEAD];
    __shared__ float sc[QR][SPAD];
    __shared__ float red[QR][33];
    __shared__ float rowstat[QR];

    const int t  = threadIdx.x;
    const int qi = t >> 5;         // 0..7
    const int g  = t & 31;         // 0..31

    if (t < 128) {                 // load q tile: 8 x 64
        const int r = t >> 4, c = (t & 15) * 4;
        *reinterpret_cast<float4*>(&qs[r][c]) = *reinterpret_cast<const float4*>(
            &q[((size_t)b * SEQ + qt * QR + r) * EDIM + hh * DHEAD + c]);
    }
    __syncthreads();

    const float* kvb = kv + (size_t)b * SEQ * EDIM + hh * DHEAD;
    const int*   xb  = x + b * SEQ;

    // phase 1: scores + local max (thread (qi,g) owns keys j = g + 32*jj)
    float lmax = -3e38f;
    for (int jj = 0; jj < 32; ++jj) {
        const int j = g + jj * 32;
        const float* kr = kvb + (size_t)j * EDIM;
        float sv = 0.f;
        #pragma unroll
        for (int d = 0; d < DHEAD; d += 4) {
            const float4 kk = *reinterpret_cast<const float4*>(&kr[d]);
            sv += qs[qi][d] * kk.x + qs[qi][d + 1] * kk.y
                + qs[qi][d + 2] * kk.z + qs[qi][d + 3] * kk.w;
        }
        if (xb[j] == 0) sv = -1e9f;
        sc[qi][j] = sv;
        lmax = fmaxf(lmax, sv);
    }
    red[qi][g] = lmax;
    __syncthreads();
    if (t < QR) {
        float mm = -3e38f;
        #pragma unroll
        for (int i = 0; i < 32; ++i) mm = fmaxf(mm, red[t][i]);
        rowstat[t] = mm;
    }
    __syncthreads();
    const float rmax = rowstat[qi];

    // exp + local sum
    float lsum = 0.f;
    for (int jj = 0; jj < 32; ++jj) {
        const int j = g + jj * 32;
        const float e = __expf(sc[qi][j] - rmax);
        sc[qi][j] = e;
        lsum += e;
    }
    red[qi][g] = lsum;
    __syncthreads();
    if (t < QR) {
        float s2 = 0.f;
        #pragma unroll
        for (int i = 0; i < 32; ++i) s2 += red[t][i];
        rowstat[t] = s2;
    }
    __syncthreads();
    const float rinv = 1.f / rowstat[qi];

    // phase 2: PV — thread (qi, dg) accumulates d = dg*2 .. dg*2+1
    const int dg = t & 31;
    float ox = 0.f, oy = 0.f;
    const float* kvd = kvb + dg * 2;
    for (int j = 0; j < SEQ; ++j) {
        const float p = sc[qi][j];
        const float2 kk = *reinterpret_cast<const float2*>(&kvd[(size_t)j * EDIM]);
        ox += p * kk.x; oy += p * kk.y;
    }
    float2 res; res.x = ox * rinv; res.y = oy * rinv;
    *reinterpret_cast<float2*>(
        &out[((size_t)b * SEQ + qt * QR + qi) * EDIM + hh * DHEAD + dg * 2]) = res;
}

// ---------------- driver ----------------
extern "C" void kernel_launch(void* const* d_in, const int* in_sizes, int n_in,
                              void* d_out, int out_size, void* d_ws, size_t ws_size,
                              hipStream_t stream)
{
    (void)in_sizes; (void)n_in; (void)out_size; (void)ws_size;

    const int*   x     = (const int*)  d_in[0];
    const float* wte   = (const float*)d_in[1];
    const float* wpe   = (const float*)d_in[2];
    const float* Wq    = (const float*)d_in[3];
    const float* bq    = (const float*)d_in[4];
    const float* Wkv   = (const float*)d_in[5];
    const float* bkv   = (const float*)d_in[6];
    const float* Wfc   = (const float*)d_in[7];
    const float* bfc   = (const float*)d_in[8];
    const float* Wproj = (const float*)d_in[9];
    const float* bproj = (const float*)d_in[10];
    const float* ln1g  = (const float*)d_in[11];
    const float* ln1b  = (const float*)d_in[12];
    const float* ln2g  = (const float*)d_in[13];
    const float* ln2b  = (const float*)d_in[14];
    const float* lnfg  = (const float*)d_in[15];
    const float* lnfb  = (const float*)d_in[16];

    const size_t SZ = (size_t)NTOK * EDIM;   // 4M floats
    float* ws  = (float*)d_ws;
    float* h   = ws;            // NTOK x E
    float* qb  = ws + 1 * SZ;   // NTOK x E
    float* kvb = ws + 2 * SZ;   // NTOK x E
    float* att = ws + 3 * SZ;   // NTOK x E
    float* u   = ws + 4 * SZ;   // NTOK x E
    float* tb  = ws + 5 * SZ;   // NTOK x 4E  (4*SZ)
    float* mb  = ws + 9 * SZ;   // NTOK x E

    embed_k<<<NTOK, 256, 0, stream>>>(x, wte, wpe, h);

    for (int l = 0; l < NLAYER; ++l) {
        const float* wq  = Wq    + (size_t)l * EDIM * EDIM;
        const float* wkv = Wkv   + (size_t)l * EDIM * EDIM;
        const float* wfc = Wfc   + (size_t)l * EDIM * 4 * EDIM;
        const float* wpj = Wproj + (size_t)l * 4 * EDIM * EDIM;

        gemm_bias_k<0><<<dim3(EDIM / 128, NTOK / 128), 256, 0, stream>>>(
            h, wq, bq + l * EDIM, qb, NTOK, EDIM, EDIM);
        gemm_bias_k<0><<<dim3(EDIM / 128, NTOK / 128), 256, 0, stream>>>(
            h, wkv, bkv + l * EDIM, kvb, NTOK, EDIM, EDIM);

        attn_k<<<dim3(SEQ / QR, NHEAD, 4), 256, 0, stream>>>(qb, kvb, x, att);

        add_ln_k<<<NTOK, 256, 0, stream>>>(h, att, ln1g + l * EDIM, ln1b + l * EDIM, u);

        gemm_bias_k<1><<<dim3(4 * EDIM / 128, NTOK / 128), 256, 0, stream>>>(
            u, wfc, bfc + l * 4 * EDIM, tb, NTOK, 4 * EDIM, EDIM);
        gemm_bias_k<0><<<dim3(EDIM / 128, NTOK / 128), 256, 0, stream>>>(
            tb, wpj, bproj + l * EDIM, mb, NTOK, EDIM, 4 * EDIM);

        add_ln_k<<<NTOK, 256, 0, stream>>>(mb, h, ln2g + l * EDIM, ln2b + l * EDIM, h);
    }

    add_ln_k<<<NTOK, 256, 0, stream>>>(h, nullptr, lnfg, lnfb, (float*)d_out);
}

// Round 2
// 6260.889 us; speedup vs baseline: 5.9706x; 5.9706x over previous
//
#include <hip/hip_runtime.h>

#define SEQ    1024
#define EDIM   1024
#define NHEAD  16
#define DHEAD  64
#define NLAYER 12
#define NTOK   4096   // B*S

typedef float f32x4  __attribute__((ext_vector_type(4)));
typedef short bf16x8 __attribute__((ext_vector_type(8)));

__device__ __forceinline__ unsigned short f32_to_bf16(float f) {
    union { float f; unsigned u; } v; v.f = f;
    return (unsigned short)((v.u + 0x7fffu + ((v.u >> 16) & 1u)) >> 16);
}
__device__ __forceinline__ unsigned pack_bf16x2(float a, float b) {
    return (unsigned)f32_to_bf16(a) | ((unsigned)f32_to_bf16(b) << 16);
}

// ---------------- embedding: h = wte[x] + wpe[s] ----------------
__global__ __launch_bounds__(256) void embed_k(
    const int* __restrict__ x, const float* __restrict__ wte,
    const float* __restrict__ wpe, float* __restrict__ h)
{
    const int bs  = blockIdx.x;            // 0..4095 (b*S + s)
    const int s   = bs & (SEQ - 1);
    const int tok = x[bs];
    const int c   = threadIdx.x * 4;
    float4 a = *reinterpret_cast<const float4*>(&wte[(size_t)tok * EDIM + c]);
    const float4 p = *reinterpret_cast<const float4*>(&wpe[(size_t)s * EDIM + c]);
    a.x += p.x; a.y += p.y; a.z += p.z; a.w += p.w;
    *reinterpret_cast<float4*>(&h[(size_t)bs * EDIM + c]) = a;
}

// ---------------- out = layernorm(x1 (+ x2), g, b) ----------------
__global__ __launch_bounds__(256) void add_ln_k(
    const float* __restrict__ x1, const float* __restrict__ x2,
    const float* __restrict__ g, const float* __restrict__ b,
    float* __restrict__ out)
{
    const int row = blockIdx.x;
    const int t   = threadIdx.x;
    const float* p1 = x1 + (size_t)row * EDIM;
    const float* p2 = x2 ? x2 + (size_t)row * EDIM : nullptr;
    float v[4];
    float s = 0.f, ss = 0.f;
    #pragma unroll
    for (int i = 0; i < 4; ++i) {
        const int c = t + i * 256;
        float a = p1[c];
        if (p2) a += p2[c];
        v[i] = a; s += a; ss += a * a;
    }
    #pragma unroll
    for (int o = 32; o > 0; o >>= 1) {
        s  += __shfl_down(s, o);
        ss += __shfl_down(ss, o);
    }
    __shared__ float rs[4], rss[4];
    const int lane = t & 63, wv = t >> 6;
    if (lane == 0) { rs[wv] = s; rss[wv] = ss; }
    __syncthreads();
    s  = rs[0] + rs[1] + rs[2] + rs[3];
    ss = rss[0] + rss[1] + rss[2] + rss[3];
    const float mean = s * (1.f / EDIM);
    const float var  = ss * (1.f / EDIM) - mean * mean;
    const float inv  = rsqrtf(var + 1e-5f);
    float* po = out + (size_t)row * EDIM;
    #pragma unroll
    for (int i = 0; i < 4; ++i) {
        const int c = t + i * 256;
        po[c] = (v[i] - mean) * inv * g[c] + b[c];
    }
}

// ---------------- GEMM: C = A(MxK,f32) @ B(KxN,f32) + bias, optional exact-gelu ----------------
template<int GELU>
__global__ __launch_bounds__(256) void gemm_bias_k(
    const float* __restrict__ A, const float* __restrict__ B,
    const float* __restrict__ bias, float* __restrict__ C,
    int M, int N, int K)
{
    __shared__ unsigned short As[128][40];
    __shared__ unsigned short Bs[32][130];

    const int t    = threadIdx.x;
    const int lane = t & 63;
    const int wave = t >> 6;
    const int wr   = wave >> 1, wc = wave & 1;
    const int lrow = lane & 15, lgrp = lane >> 4;
    const int row0 = blockIdx.y * 128, col0 = blockIdx.x * 128;

    f32x4 acc[4][4];
    #pragma unroll
    for (int i = 0; i < 4; ++i)
        #pragma unroll
        for (int j = 0; j < 4; ++j)
            acc[i][j] = (f32x4){0.f, 0.f, 0.f, 0.f};

    for (int k0 = 0; k0 < K; k0 += 32) {
        #pragma unroll
        for (int i = 0; i < 4; ++i) {
            const int flat = t + i * 256;
            const int ar = flat >> 3, ac = (flat & 7) * 4;
            const float4 v = *reinterpret_cast<const float4*>(
                &A[(size_t)(row0 + ar) * K + k0 + ac]);
            unsigned* dst = reinterpret_cast<unsigned*>(&As[ar][ac]);
            dst[0] = pack_bf16x2(v.x, v.y);
            dst[1] = pack_bf16x2(v.z, v.w);
        }
        #pragma unroll
        for (int i = 0; i < 4; ++i) {
            const int flat = t + i * 256;
            const int br = flat >> 5, bc = (flat & 31) * 4;
            const float4 v = *reinterpret_cast<const float4*>(
                &B[(size_t)(k0 + br) * N + col0 + bc]);
            unsigned* dst = reinterpret_cast<unsigned*>(&Bs[br][bc]);
            dst[0] = pack_bf16x2(v.x, v.y);
            dst[1] = pack_bf16x2(v.z, v.w);
        }
        __syncthreads();

        bf16x8 af[4];
        #pragma unroll
        for (int m = 0; m < 4; ++m)
            af[m] = *reinterpret_cast<const bf16x8*>(
                &As[wr * 64 + m * 16 + lrow][lgrp * 8]);

        #pragma unroll
        for (int n = 0; n < 4; ++n) {
            const int bcol = wc * 64 + n * 16 + lrow;
            bf16x8 bfr;
            #pragma unroll
            for (int j = 0; j < 8; ++j)
                bfr[j] = (short)Bs[lgrp * 8 + j][bcol];
            #pragma unroll
            for (int m = 0; m < 4; ++m)
                acc[m][n] = __builtin_amdgcn_mfma_f32_16x16x32_bf16(
                    af[m], bfr, acc[m][n], 0, 0, 0);
        }
        __syncthreads();
    }

    #pragma unroll
    for (int n = 0; n < 4; ++n) {
        const int col = col0 + wc * 64 + n * 16 + lrow;
        const float bv = bias[col];
        #pragma unroll
        for (int m = 0; m < 4; ++m) {
            const int rbase = row0 + wr * 64 + m * 16 + lgrp * 4;
            #pragma unroll
            for (int r = 0; r < 4; ++r) {
                float xv = acc[m][n][r] + bv;
                if (GELU) xv = 0.5f * xv * (1.f + erff(xv * 0.70710678118654752f));
                C[(size_t)(rbase + r) * N + col] = xv;
            }
        }
    }
}

// ---------------- flash attention, bf16 MFMA, online softmax ----------------
// grid (S/128, H, B); block 256 = 4 waves; wave owns 32 q-rows; KV tile = 64 keys.
// scores unscaled, key-padding mask = replacement with -1e9, K==V (shared kv).
#define KVPAD 68
__global__ __launch_bounds__(256) void attn_k(
    const float* __restrict__ q, const float* __restrict__ kv,
    const int* __restrict__ x, float* __restrict__ out)
{
    __shared__ unsigned short KVr[64][KVPAD];      // [key][d] bf16
    __shared__ unsigned short Ps[4][32][KVPAD];    // per-wave P tile [row][key] bf16
    __shared__ float maskf[64];

    const int qt = blockIdx.x;       // q-tile of 128 rows
    const int hh = blockIdx.y;
    const int b  = blockIdx.z;

    const int t    = threadIdx.x;
    const int w    = t >> 6;
    const int lane = t & 63;
    const int lrow = lane & 15, lgrp = lane >> 4;

    const float* qb  = q  + ((size_t)b * SEQ) * EDIM + hh * DHEAD;
    const float* kvb = kv + ((size_t)b * SEQ) * EDIM + hh * DHEAD;
    const int*   xb  = x + b * SEQ;
    const int qrow0 = qt * 128 + w * 32;

    // ---- load Q fragments (A-frags), rows qrow0 + m*16 + lrow, k = ks*32 + lgrp*8 + j
    bf16x8 qf[2][2];
    #pragma unroll
    for (int m = 0; m < 2; ++m)
        #pragma unroll
        for (int ks = 0; ks < 2; ++ks) {
            const float* p = qb + (size_t)(qrow0 + m * 16 + lrow) * EDIM + ks * 32 + lgrp * 8;
            const float4 a  = *reinterpret_cast<const float4*>(p);
            const float4 b2 = *reinterpret_cast<const float4*>(p + 4);
            unsigned* u = reinterpret_cast<unsigned*>(&qf[m][ks]);
            u[0] = pack_bf16x2(a.x, a.y);  u[1] = pack_bf16x2(a.z, a.w);
            u[2] = pack_bf16x2(b2.x, b2.y); u[3] = pack_bf16x2(b2.z, b2.w);
        }

    f32x4 O[2][4];
    float mrun[2][4], lrun[2][4];
    #pragma unroll
    for (int m = 0; m < 2; ++m)
        #pragma unroll
        for (int i = 0; i < 4; ++i) {
            O[m][i] = (f32x4){0.f, 0.f, 0.f, 0.f};
            mrun[m][i] = -3e30f; lrun[m][i] = 0.f;
        }

    for (int kt = 0; kt < SEQ / 64; ++kt) {
        __syncthreads();
        // stage KV tile 64x64 f32 -> bf16
        #pragma unroll
        for (int i = 0; i < 4; ++i) {
            const int flat = t + i * 256;
            const int kr = flat >> 4, kc = (flat & 15) * 4;
            const float4 v = *reinterpret_cast<const float4*>(
                &kvb[(size_t)(kt * 64 + kr) * EDIM + kc]);
            unsigned* dst = reinterpret_cast<unsigned*>(&KVr[kr][kc]);
            dst[0] = pack_bf16x2(v.x, v.y);
            dst[1] = pack_bf16x2(v.z, v.w);
        }
        if (t < 64) maskf[t] = (xb[kt * 64 + t] != 0) ? 1.f : 0.f;
        __syncthreads();

        // ---- QK^T: S[2m][4n] (col = key = 16n+lrow, row = 16m+4*lgrp+r)
        f32x4 s[2][4];
        #pragma unroll
        for (int m = 0; m < 2; ++m)
            #pragma unroll
            for (int n = 0; n < 4; ++n) s[m][n] = (f32x4){0.f, 0.f, 0.f, 0.f};
        #pragma unroll
        for (int ks = 0; ks < 2; ++ks)
            #pragma unroll
            for (int n = 0; n < 4; ++n) {
                const bf16x8 bv = *reinterpret_cast<const bf16x8*>(
                    &KVr[16 * n + lrow][ks * 32 + lgrp * 8]);
                #pragma unroll
                for (int m = 0; m < 2; ++m)
                    s[m][n] = __builtin_amdgcn_mfma_f32_16x16x32_bf16(
                        qf[m][ks], bv, s[m][n], 0, 0, 0);
            }

        // ---- mask (replacement semantics, as in reference)
        #pragma unroll
        for (int n = 0; n < 4; ++n) {
            const float flag = maskf[16 * n + lrow];
            #pragma unroll
            for (int m = 0; m < 2; ++m)
                #pragma unroll
                for (int r = 0; r < 4; ++r)
                    s[m][n][r] = (flag != 0.f) ? s[m][n][r] : -1e9f;
        }

        // ---- online softmax update
        #pragma unroll
        for (int m = 0; m < 2; ++m)
            #pragma unroll
            for (int r = 0; r < 4; ++r) {
                float v = fmaxf(fmaxf(s[m][0][r], s[m][1][r]),
                                fmaxf(s[m][2][r], s[m][3][r]));
                #pragma unroll
                for (int o = 1; o < 16; o <<= 1) v = fmaxf(v, __shfl_xor(v, o));
                const float mn = fmaxf(mrun[m][r], v);
                const float fs = __expf(mrun[m][r] - mn);
                mrun[m][r] = mn;
                lrun[m][r] *= fs;
                #pragma unroll
                for (int df = 0; df < 4; ++df) O[m][df][r] *= fs;
            }

        // ---- p = exp(s - m), row sums, write P to per-wave LDS
        #pragma unroll
        for (int m = 0; m < 2; ++m) {
            float rsum[4] = {0.f, 0.f, 0.f, 0.f};
            #pragma unroll
            for (int n = 0; n < 4; ++n)
                #pragma unroll
                for (int r = 0; r < 4; ++r) {
                    const float p = __expf(s[m][n][r] - mrun[m][r]);
                    rsum[r] += p;
                    Ps[w][m * 16 + 4 * lgrp + r][16 * n + lrow] = f32_to_bf16(p);
                }
            #pragma unroll
            for (int r = 0; r < 4; ++r) {
                float v = rsum[r];
                #pragma unroll
                for (int o = 1; o < 16; o <<= 1) v += __shfl_xor(v, o);
                lrun[m][r] += v;
            }
        }

        // ---- PV: O += P @ KV   (A = P from LDS, B = KV column gather)
        #pragma unroll
        for (int ks = 0; ks < 2; ++ks) {
            bf16x8 paf[2];
            #pragma unroll
            for (int m = 0; m < 2; ++m)
                paf[m] = *reinterpret_cast<const bf16x8*>(
                    &Ps[w][m * 16 + lrow][ks * 32 + lgrp * 8]);
            #pragma unroll
            for (int df = 0; df < 4; ++df) {
                bf16x8 bvf;
                #pragma unroll
                for (int j = 0; j < 8; ++j)
                    bvf[j] = (short)KVr[ks * 32 + lgrp * 8 + j][16 * df + lrow];
                #pragma unroll
                for (int m = 0; m < 2; ++m)
                    O[m][df] = __builtin_amdgcn_mfma_f32_16x16x32_bf16(
                        paf[m], bvf, O[m][df], 0, 0, 0);
            }
        }
    }

    // ---- normalize and write out (f32)
    #pragma unroll
    for (int m = 0; m < 2; ++m)
        #pragma unroll
        for (int r = 0; r < 4; ++r) {
            const float inv = 1.f / lrun[m][r];
            const int row = qrow0 + m * 16 + 4 * lgrp + r;
            float* po = out + ((size_t)b * SEQ + row) * EDIM + hh * DHEAD;
            #pragma unroll
            for (int df = 0; df < 4; ++df)
                po[16 * df + lrow] = O[m][df][r] * inv;
        }
}

// ---------------- driver ----------------
extern "C" void kernel_launch(void* const* d_in, const int* in_sizes, int n_in,
                              void* d_out, int out_size, void* d_ws, size_t ws_size,
                              hipStream_t stream)
{
    (void)in_sizes; (void)n_in; (void)out_size; (void)ws_size;

    const int*   x     = (const int*)  d_in[0];
    const float* wte   = (const float*)d_in[1];
    const float* wpe   = (const float*)d_in[2];
    const float* Wq    = (const float*)d_in[3];
    const float* bq    = (const float*)d_in[4];
    const float* Wkv   = (const float*)d_in[5];
    const float* bkv   = (const float*)d_in[6];
    const float* Wfc   = (const float*)d_in[7];
    const float* bfc   = (const float*)d_in[8];
    const float* Wproj = (const float*)d_in[9];
    const float* bproj = (const float*)d_in[10];
    const float* ln1g  = (const float*)d_in[11];
    const float* ln1b  = (const float*)d_in[12];
    const float* ln2g  = (const float*)d_in[13];
    const float* ln2b  = (const float*)d_in[14];
    const float* lnfg  = (const float*)d_in[15];
    const float* lnfb  = (const float*)d_in[16];

    const size_t SZ = (size_t)NTOK * EDIM;
    float* ws  = (float*)d_ws;
    float* h   = ws;
    float* qb  = ws + 1 * SZ;
    float* kvb = ws + 2 * SZ;
    float* att = ws + 3 * SZ;
    float* u   = ws + 4 * SZ;
    float* tb  = ws + 5 * SZ;   // NTOK x 4E
    float* mb  = ws + 9 * SZ;

    embed_k<<<NTOK, 256, 0, stream>>>(x, wte, wpe, h);

    for (int l = 0; l < NLAYER; ++l) {
        const float* wq  = Wq    + (size_t)l * EDIM * EDIM;
        const float* wkv = Wkv   + (size_t)l * EDIM * EDIM;
        const float* wfc = Wfc   + (size_t)l * EDIM * 4 * EDIM;
        const float* wpj = Wproj + (size_t)l * 4 * EDIM * EDIM;

        gemm_bias_k<0><<<dim3(EDIM / 128, NTOK / 128), 256, 0, stream>>>(
            h, wq, bq + l * EDIM, qb, NTOK, EDIM, EDIM);
        gemm_bias_k<0><<<dim3(EDIM / 128, NTOK / 128), 256, 0, stream>>>(
            h, wkv, bkv + l * EDIM, kvb, NTOK, EDIM, EDIM);

        attn_k<<<dim3(SEQ / 128, NHEAD, 4), 256, 0, stream>>>(qb, kvb, x, att);

        add_ln_k<<<NTOK, 256, 0, stream>>>(h, att, ln1g + l * EDIM, ln1b + l * EDIM, u);

        gemm_bias_k<1><<<dim3(4 * EDIM / 128, NTOK / 128), 256, 0, stream>>>(
            u, wfc, bfc + l * 4 * EDIM, tb, NTOK, 4 * EDIM, EDIM);
        gemm_bias_k<0><<<dim3(EDIM / 128, NTOK / 128), 256, 0, stream>>>(
            tb, wpj, bproj + l * EDIM, mb, NTOK, EDIM, 4 * EDIM);

        add_ln_k<<<NTOK, 256, 0, stream>>>(mb, h, ln2g + l * EDIM, ln2b + l * EDIM, h);
    }

    add_ln_k<<<NTOK, 256, 0, stream>>>(h, nullptr, lnfg, lnfb, (float*)d_out);
}

// Round 3
// 3737.495 us; speedup vs baseline: 10.0017x; 1.6752x over previous
//
#include <hip/hip_runtime.h>

#define SEQ    1024
#define EDIM   1024
#define NHEAD  16
#define DHEAD  64
#define NLAYER 12
#define NTOK   4096   // B*S

typedef float f32x4  __attribute__((ext_vector_type(4)));
typedef short bf16x8 __attribute__((ext_vector_type(8)));

__device__ __forceinline__ unsigned short f32_to_bf16(float f) {
    union { float f; unsigned u; } v; v.f = f;
    return (unsigned short)((v.u + 0x7fffu + ((v.u >> 16) & 1u)) >> 16);
}

__device__ __forceinline__ void gload_lds16(const unsigned short* g, unsigned short* l) {
    __builtin_amdgcn_global_load_lds((const __attribute__((address_space(1))) void*)g,
                                     (__attribute__((address_space(3))) void*)l, 16, 0, 0);
}

// ---------------- weight prep: W [K][N] f32 -> WT [N][K] bf16 ----------------
__global__ __launch_bounds__(256) void transpose_bf16_k(
    const float* __restrict__ W, unsigned short* __restrict__ WT, int K, int N)
{
    __shared__ float tile[32][33];
    const int n0 = blockIdx.x * 32, k0 = blockIdx.y * 32;
    const int t = threadIdx.x;
    const int r = t >> 3, c4 = (t & 7) * 4;
    const float4 v = *reinterpret_cast<const float4*>(&W[(size_t)(k0 + r) * N + n0 + c4]);
    tile[r][c4 + 0] = v.x; tile[r][c4 + 1] = v.y;
    tile[r][c4 + 2] = v.z; tile[r][c4 + 3] = v.w;
    __syncthreads();
    ushort4 o;
    o.x = f32_to_bf16(tile[c4 + 0][r]);
    o.y = f32_to_bf16(tile[c4 + 1][r]);
    o.z = f32_to_bf16(tile[c4 + 2][r]);
    o.w = f32_to_bf16(tile[c4 + 3][r]);
    *reinterpret_cast<ushort4*>(&WT[(size_t)(n0 + r) * K + k0 + c4]) = o;
}

// ---------------- embedding: h = wte[x] + wpe[s]  (f32 + bf16 copies) ----------------
__global__ __launch_bounds__(256) void embed_k(
    const int* __restrict__ x, const float* __restrict__ wte,
    const float* __restrict__ wpe, float* __restrict__ h,
    unsigned short* __restrict__ hb)
{
    const int bs  = blockIdx.x;
    const int s   = bs & (SEQ - 1);
    const int tok = x[bs];
    const int c   = threadIdx.x * 4;
    float4 a = *reinterpret_cast<const float4*>(&wte[(size_t)tok * EDIM + c]);
    const float4 p = *reinterpret_cast<const float4*>(&wpe[(size_t)s * EDIM + c]);
    a.x += p.x; a.y += p.y; a.z += p.z; a.w += p.w;
    *reinterpret_cast<float4*>(&h[(size_t)bs * EDIM + c]) = a;
    ushort4 o;
    o.x = f32_to_bf16(a.x); o.y = f32_to_bf16(a.y);
    o.z = f32_to_bf16(a.z); o.w = f32_to_bf16(a.w);
    *reinterpret_cast<ushort4*>(&hb[(size_t)bs * EDIM + c]) = o;
}

// ---------------- layernorm(x1 (+ x2)) -> optional f32 out, optional bf16 out ----------------
template<int WF32, int WBF16>
__global__ __launch_bounds__(256) void add_ln_k(
    const float* __restrict__ x1, const float* __restrict__ x2,
    const float* __restrict__ g, const float* __restrict__ b,
    float* __restrict__ outf, unsigned short* __restrict__ outb)
{
    const int row = blockIdx.x;
    const int t   = threadIdx.x;
    const float* p1 = x1 + (size_t)row * EDIM;
    const float* p2 = x2 ? x2 + (size_t)row * EDIM : nullptr;
    float v[4];
    float s = 0.f, ss = 0.f;
    #pragma unroll
    for (int i = 0; i < 4; ++i) {
        const int c = t + i * 256;
        float a = p1[c];
        if (p2) a += p2[c];
        v[i] = a; s += a; ss += a * a;
    }
    #pragma unroll
    for (int o = 32; o > 0; o >>= 1) {
        s  += __shfl_down(s, o);
        ss += __shfl_down(ss, o);
    }
    __shared__ float rs[4], rss[4];
    const int lane = t & 63, wv = t >> 6;
    if (lane == 0) { rs[wv] = s; rss[wv] = ss; }
    __syncthreads();
    s  = rs[0] + rs[1] + rs[2] + rs[3];
    ss = rss[0] + rss[1] + rss[2] + rss[3];
    const float mean = s * (1.f / EDIM);
    const float var  = ss * (1.f / EDIM) - mean * mean;
    const float inv  = rsqrtf(var + 1e-5f);
    #pragma unroll
    for (int i = 0; i < 4; ++i) {
        const int c = t + i * 256;
        const float y = (v[i] - mean) * inv * g[c] + b[c];
        if (WF32)  outf[(size_t)row * EDIM + c] = y;
        if (WBF16) outb[(size_t)row * EDIM + c] = f32_to_bf16(y);
    }
}

// ---------------- GEMM (m97 structure): C = A(bf16 MxK) @ BT(bf16 NxK)^T + bias ----------------
// 128x128 tile, BK=32, 4 waves x (64x64), global_load_lds width-16, ds_read_b128 frags.
template<int GELU, int OUTBF16>
__global__ __launch_bounds__(256) void gemm_bt_k(
    const unsigned short* __restrict__ A,
    const unsigned short* __restrict__ BT,
    const float* __restrict__ bias, void* __restrict__ Cout,
    int M, int N, int K)
{
    __shared__ unsigned short As[128 * 32];
    __shared__ unsigned short Bs[128 * 32];

    const int t    = threadIdx.x;
    const int lane = t & 63;
    const int wave = t >> 6;
    const int wr   = wave >> 1, wc = wave & 1;
    const int lrow = lane & 15, lgrp = lane >> 4;
    const int row0 = blockIdx.y * 128, col0 = blockIdx.x * 128;

    // staging geometry: wave stages chunks {2w, 2w+1} of each tile (16 rows / chunk)
    const int srow  = lane >> 2;          // 0..15
    const int skoff = (lane & 3) * 8;     // k-element offset of the 16B piece
    const unsigned short* aP0 = A  + (size_t)(row0 + 32 * wave + srow) * K + skoff;
    const unsigned short* aP1 = aP0 + (size_t)16 * K;
    const unsigned short* bP0 = BT + (size_t)(col0 + 32 * wave + srow) * K + skoff;
    const unsigned short* bP1 = bP0 + (size_t)16 * K;
    unsigned short* aL0 = As + wave * 1024;
    unsigned short* aL1 = As + wave * 1024 + 512;
    unsigned short* bL0 = Bs + wave * 1024;
    unsigned short* bL1 = Bs + wave * 1024 + 512;

    f32x4 acc[4][4];
    #pragma unroll
    for (int i = 0; i < 4; ++i)
        #pragma unroll
        for (int j = 0; j < 4; ++j)
            acc[i][j] = (f32x4){0.f, 0.f, 0.f, 0.f};

    for (int k0 = 0; k0 < K; k0 += 32) {
        gload_lds16(aP0 + k0, aL0);
        gload_lds16(aP1 + k0, aL1);
        gload_lds16(bP0 + k0, bL0);
        gload_lds16(bP1 + k0, bL1);
        __syncthreads();   // drains vmcnt -> staged tile visible

        bf16x8 af[4], bf[4];
        #pragma unroll
        for (int m = 0; m < 4; ++m)
            af[m] = *reinterpret_cast<const bf16x8*>(
                &As[(wr * 64 + m * 16 + lrow) * 32 + lgrp * 8]);
        #pragma unroll
        for (int n = 0; n < 4; ++n)
            bf[n] = *reinterpret_cast<const bf16x8*>(
                &Bs[(wc * 64 + n * 16 + lrow) * 32 + lgrp * 8]);

        #pragma unroll
        for (int n = 0; n < 4; ++n)
            #pragma unroll
            for (int m = 0; m < 4; ++m)
                acc[m][n] = __builtin_amdgcn_mfma_f32_16x16x32_bf16(
                    af[m], bf[n], acc[m][n], 0, 0, 0);
        __syncthreads();   // frag reads done before next-iter staging overwrites
    }

    #pragma unroll
    for (int n = 0; n < 4; ++n) {
        const int col = col0 + wc * 64 + n * 16 + lrow;
        const float bv = bias[col];
        #pragma unroll
        for (int m = 0; m < 4; ++m) {
            const int rb = row0 + wr * 64 + m * 16 + lgrp * 4;
            #pragma unroll
            for (int r = 0; r < 4; ++r) {
                float xv = acc[m][n][r] + bv;
                if (GELU) xv = 0.5f * xv * (1.f + erff(xv * 0.70710678118654752f));
                if (OUTBF16)
                    ((unsigned short*)Cout)[(size_t)(rb + r) * N + col] = f32_to_bf16(xv);
                else
                    ((float*)Cout)[(size_t)(rb + r) * N + col] = xv;
            }
        }
    }
}

// ---------------- flash attention, bf16 inputs, online softmax ----------------
#define KVPAD 68
__global__ __launch_bounds__(256) void attn_k(
    const unsigned short* __restrict__ q, const unsigned short* __restrict__ kv,
    const int* __restrict__ x, float* __restrict__ out)
{
    __shared__ unsigned short KVr[64][KVPAD];
    __shared__ unsigned short Ps[4][32][KVPAD];
    __shared__ float maskf[64];

    const int qt = blockIdx.x;
    const int hh = blockIdx.y;
    const int b  = blockIdx.z;

    const int t    = threadIdx.x;
    const int w    = t >> 6;
    const int lane = t & 63;
    const int lrow = lane & 15, lgrp = lane >> 4;

    const unsigned short* qb_  = q  + ((size_t)b * SEQ) * EDIM + hh * DHEAD;
    const unsigned short* kvb_ = kv + ((size_t)b * SEQ) * EDIM + hh * DHEAD;
    const int* xb = x + b * SEQ;
    const int qrow0 = qt * 128 + w * 32;

    bf16x8 qf[2][2];
    #pragma unroll
    for (int m = 0; m < 2; ++m)
        #pragma unroll
        for (int ks = 0; ks < 2; ++ks)
            qf[m][ks] = *reinterpret_cast<const bf16x8*>(
                qb_ + (size_t)(qrow0 + m * 16 + lrow) * EDIM + ks * 32 + lgrp * 8);

    f32x4 O[2][4];
    float mrun[2][4], lrun[2][4];
    #pragma unroll
    for (int m = 0; m < 2; ++m)
        #pragma unroll
        for (int i = 0; i < 4; ++i) {
            O[m][i] = (f32x4){0.f, 0.f, 0.f, 0.f};
            mrun[m][i] = -3e30f; lrun[m][i] = 0.f;
        }

    for (int kt = 0; kt < SEQ / 64; ++kt) {
        __syncthreads();
        // stage KV tile 64x64 bf16 (8B pieces; pad 68 keeps conflicts ~free)
        #pragma unroll
        for (int i = 0; i < 4; ++i) {
            const int u2 = t + i * 256;
            const int kr = u2 >> 4, kc = (u2 & 15) * 4;
            *reinterpret_cast<ushort4*>(&KVr[kr][kc]) =
                *reinterpret_cast<const ushort4*>(
                    &kvb_[(size_t)(kt * 64 + kr) * EDIM + kc]);
        }
        if (t < 64) maskf[t] = (xb[kt * 64 + t] != 0) ? 1.f : 0.f;
        __syncthreads();

        // QK^T
        f32x4 s[2][4];
        #pragma unroll
        for (int m = 0; m < 2; ++m)
            #pragma unroll
            for (int n = 0; n < 4; ++n) s[m][n] = (f32x4){0.f, 0.f, 0.f, 0.f};
        #pragma unroll
        for (int ks = 0; ks < 2; ++ks)
            #pragma unroll
            for (int n = 0; n < 4; ++n) {
                union { bf16x8 v; ushort4 h[2]; } bb;
                bb.h[0] = *reinterpret_cast<const ushort4*>(
                    &KVr[16 * n + lrow][ks * 32 + lgrp * 8]);
                bb.h[1] = *reinterpret_cast<const ushort4*>(
                    &KVr[16 * n + lrow][ks * 32 + lgrp * 8 + 4]);
                #pragma unroll
                for (int m = 0; m < 2; ++m)
                    s[m][n] = __builtin_amdgcn_mfma_f32_16x16x32_bf16(
                        qf[m][ks], bb.v, s[m][n], 0, 0, 0);
            }

        // mask (replacement semantics)
        #pragma unroll
        for (int n = 0; n < 4; ++n) {
            const float flag = maskf[16 * n + lrow];
            #pragma unroll
            for (int m = 0; m < 2; ++m)
                #pragma unroll
                for (int r = 0; r < 4; ++r)
                    s[m][n][r] = (flag != 0.f) ? s[m][n][r] : -1e9f;
        }

        // online softmax
        #pragma unroll
        for (int m = 0; m < 2; ++m)
            #pragma unroll
            for (int r = 0; r < 4; ++r) {
                float v = fmaxf(fmaxf(s[m][0][r], s[m][1][r]),
                                fmaxf(s[m][2][r], s[m][3][r]));
                #pragma unroll
                for (int o = 1; o < 16; o <<= 1) v = fmaxf(v, __shfl_xor(v, o));
                const float mn = fmaxf(mrun[m][r], v);
                const float fs = __expf(mrun[m][r] - mn);
                mrun[m][r] = mn;
                lrun[m][r] *= fs;
                #pragma unroll
                for (int df = 0; df < 4; ++df) O[m][df][r] *= fs;
            }

        #pragma unroll
        for (int m = 0; m < 2; ++m) {
            float rsum[4] = {0.f, 0.f, 0.f, 0.f};
            #pragma unroll
            for (int n = 0; n < 4; ++n)
                #pragma unroll
                for (int r = 0; r < 4; ++r) {
                    const float p = __expf(s[m][n][r] - mrun[m][r]);
                    rsum[r] += p;
                    Ps[w][m * 16 + 4 * lgrp + r][16 * n + lrow] = f32_to_bf16(p);
                }
            #pragma unroll
            for (int r = 0; r < 4; ++r) {
                float v = rsum[r];
                #pragma unroll
                for (int o = 1; o < 16; o <<= 1) v += __shfl_xor(v, o);
                lrun[m][r] += v;
            }
        }

        // PV
        #pragma unroll
        for (int ks = 0; ks < 2; ++ks) {
            bf16x8 paf[2];
            #pragma unroll
            for (int m = 0; m < 2; ++m) {
                union { bf16x8 v; ushort4 h[2]; } pp;
                pp.h[0] = *reinterpret_cast<const ushort4*>(
                    &Ps[w][m * 16 + lrow][ks * 32 + lgrp * 8]);
                pp.h[1] = *reinterpret_cast<const ushort4*>(
                    &Ps[w][m * 16 + lrow][ks * 32 + lgrp * 8 + 4]);
                paf[m] = pp.v;
            }
            #pragma unroll
            for (int df = 0; df < 4; ++df) {
                bf16x8 bvf;
                #pragma unroll
                for (int j = 0; j < 8; ++j)
                    bvf[j] = (short)KVr[ks * 32 + lgrp * 8 + j][16 * df + lrow];
                #pragma unroll
                for (int m = 0; m < 2; ++m)
                    O[m][df] = __builtin_amdgcn_mfma_f32_16x16x32_bf16(
                        paf[m], bvf, O[m][df], 0, 0, 0);
            }
        }
    }

    #pragma unroll
    for (int m = 0; m < 2; ++m)
        #pragma unroll
        for (int r = 0; r < 4; ++r) {
            const float inv = 1.f / lrun[m][r];
            const int row = qrow0 + m * 16 + 4 * lgrp + r;
            float* po = out + ((size_t)b * SEQ + row) * EDIM + hh * DHEAD;
            #pragma unroll
            for (int df = 0; df < 4; ++df)
                po[16 * df + lrow] = O[m][df][r] * inv;
        }
}

// ---------------- driver ----------------
extern "C" void kernel_launch(void* const* d_in, const int* in_sizes, int n_in,
                              void* d_out, int out_size, void* d_ws, size_t ws_size,
                              hipStream_t stream)
{
    (void)in_sizes; (void)n_in; (void)out_size; (void)ws_size;

    const int*   x     = (const int*)  d_in[0];
    const float* wte   = (const float*)d_in[1];
    const float* wpe   = (const float*)d_in[2];
    const float* Wq    = (const float*)d_in[3];
    const float* bq    = (const float*)d_in[4];
    const float* Wkv   = (const float*)d_in[5];
    const float* bkv   = (const float*)d_in[6];
    const float* Wfc   = (const float*)d_in[7];
    const float* bfc   = (const float*)d_in[8];
    const float* Wproj = (const float*)d_in[9];
    const float* bproj = (const float*)d_in[10];
    const float* ln1g  = (const float*)d_in[11];
    const float* ln1b  = (const float*)d_in[12];
    const float* ln2g  = (const float*)d_in[13];
    const float* ln2b  = (const float*)d_in[14];
    const float* lnfg  = (const float*)d_in[15];
    const float* lnfb  = (const float*)d_in[16];

    const size_t MB = 1024 * 1024;
    char* W = (char*)d_ws;
    float*          h    = (float*)(W + 0 * MB);            // 16 MB
    float*          att  = (float*)(W + 16 * MB);           // 16 MB
    float*          mb   = (float*)(W + 32 * MB);           // 16 MB
    unsigned short* hb   = (unsigned short*)(W + 48 * MB);  // 8 MB
    unsigned short* qb   = (unsigned short*)(W + 56 * MB);  // 8 MB
    unsigned short* kvb  = (unsigned short*)(W + 64 * MB);  // 8 MB
    unsigned short* ub   = (unsigned short*)(W + 72 * MB);  // 8 MB
    unsigned short* tb   = (unsigned short*)(W + 80 * MB);  // 32 MB
    unsigned short* wqT  = (unsigned short*)(W + 112 * MB); // 2 MB
    unsigned short* wkvT = (unsigned short*)(W + 114 * MB); // 2 MB
    unsigned short* wfcT = (unsigned short*)(W + 116 * MB); // 8 MB
    unsigned short* wpjT = (unsigned short*)(W + 124 * MB); // 8 MB (end 132 MB)

    embed_k<<<NTOK, 256, 0, stream>>>(x, wte, wpe, h, hb);

    for (int l = 0; l < NLAYER; ++l) {
        const float* wq  = Wq    + (size_t)l * EDIM * EDIM;
        const float* wkv = Wkv   + (size_t)l * EDIM * EDIM;
        const float* wfc = Wfc   + (size_t)l * EDIM * 4 * EDIM;
        const float* wpj = Wproj + (size_t)l * 4 * EDIM * EDIM;

        transpose_bf16_k<<<dim3(EDIM / 32, EDIM / 32), 256, 0, stream>>>(
            wq, wqT, EDIM, EDIM);
        transpose_bf16_k<<<dim3(EDIM / 32, EDIM / 32), 256, 0, stream>>>(
            wkv, wkvT, EDIM, EDIM);
        transpose_bf16_k<<<dim3(4 * EDIM / 32, EDIM / 32), 256, 0, stream>>>(
            wfc, wfcT, EDIM, 4 * EDIM);
        transpose_bf16_k<<<dim3(EDIM / 32, 4 * EDIM / 32), 256, 0, stream>>>(
            wpj, wpjT, 4 * EDIM, EDIM);

        gemm_bt_k<0, 1><<<dim3(EDIM / 128, NTOK / 128), 256, 0, stream>>>(
            hb, wqT, bq + l * EDIM, qb, NTOK, EDIM, EDIM);
        gemm_bt_k<0, 1><<<dim3(EDIM / 128, NTOK / 128), 256, 0, stream>>>(
            hb, wkvT, bkv + l * EDIM, kvb, NTOK, EDIM, EDIM);

        attn_k<<<dim3(SEQ / 128, NHEAD, 4), 256, 0, stream>>>(qb, kvb, x, att);

        add_ln_k<0, 1><<<NTOK, 256, 0, stream>>>(
            h, att, ln1g + l * EDIM, ln1b + l * EDIM, nullptr, ub);

        gemm_bt_k<1, 1><<<dim3(4 * EDIM / 128, NTOK / 128), 256, 0, stream>>>(
            ub, wfcT, bfc + l * 4 * EDIM, tb, NTOK, 4 * EDIM, EDIM);
        gemm_bt_k<0, 0><<<dim3(EDIM / 128, NTOK / 128), 256, 0, stream>>>(
            tb, wpjT, bproj + l * EDIM, mb, NTOK, EDIM, 4 * EDIM);

        add_ln_k<1, 1><<<NTOK, 256, 0, stream>>>(
            mb, h, ln2g + l * EDIM, ln2b + l * EDIM, h, hb);
    }

    add_ln_k<1, 0><<<NTOK, 256, 0, stream>>>(
        h, nullptr, lnfg, lnfb, (float*)d_out, nullptr);
}